// Round 9
// baseline (630.491 us; speedup 1.0000x reference)
//
#include <hip/hip_runtime.h>
#include <hip/hip_bf16.h>
#include <math.h>

#define S_LEN 2048
#define NHEAD 16
#define DMODEL 1024

typedef short bf16x8 __attribute__((ext_vector_type(8)));
typedef float f32x4 __attribute__((ext_vector_type(4)));

__device__ __forceinline__ unsigned short bfbits(float x) {
    __hip_bfloat16 h = __float2bfloat16(x);   // round-to-nearest
    unsigned short u; __builtin_memcpy(&u, &h, 2); return u;
}
__device__ __forceinline__ float bf2f(unsigned short u) {
    union { unsigned int i; float f; } v; v.i = ((unsigned int)u) << 16; return v.f;
}
// round-to-nearest split: x ~= hi + lo with rel error ~2^-18
__device__ __forceinline__ void splitRN(float x, unsigned short& hi, unsigned short& lo) {
    unsigned short h = bfbits(x);
    float r = x - bf2f(h);
    hi = h; lo = bfbits(r);
}

__device__ __forceinline__ int mask_at(const void* mp, int enc, int s) {
    if (enc) return ((const unsigned char*)mp)[s] != 0;
    return ((const unsigned int*)mp)[s] != 0u;
}

__global__ void detect_kernel(const void* __restrict__ mask, int* __restrict__ flags) {
    if (threadIdx.x == 0 && blockIdx.x == 0) {
        const unsigned int* m = (const unsigned int*)mask;
        int bytey = 0;
        for (int i = 0; i < 8; ++i) {
            unsigned int u = m[i];
            if (u != 0u && u != 1u && u != 0x3F800000u) bytey = 1;
        }
        flags[0] = bytey;
    }
}

// MFMA projection, split-bf16 4-MFMA, in-LDS RN split (each element split once per block).
// mode 1: rope(x)*b_rotate -> hi/lo bf16 [h][s][d]. mode 0: plain -> hi/lo bf16 [h][d][s] (transposed).
// grid (16 heads, 32 s-tiles), 256 threads = 4 waves (d-tiles).
__global__ __launch_bounds__(256)
void proj_mfma(const float* __restrict__ X, const float* __restrict__ b_emb,
               const float* __restrict__ ll, const float* __restrict__ bproj,
               unsigned short* __restrict__ out_hi, unsigned short* __restrict__ out_lo,
               int woff, int mode) {
    __shared__ unsigned short Xh[64][40], Xl[64][40];   // X tile: [s][k]
    __shared__ unsigned short Bh_[64][40], Bl_[64][40]; // b_emb tile
    __shared__ unsigned short Wh[64][40], Wl[64][40];   // W^T tile: [n(head-dim)][k]
    __shared__ unsigned short Ph[64][40], Pl[64][40];   // bproj^T tile
    const int t = threadIdx.x;
    const int h = blockIdx.x;
    const int s0 = blockIdx.y * 64;
    const int lane = t & 63, dt = t >> 6, quad = lane >> 4, c = lane & 15;
    const int dorope = mode;

    f32x4 accx[4] = {{0.f,0.f,0.f,0.f},{0.f,0.f,0.f,0.f},{0.f,0.f,0.f,0.f},{0.f,0.f,0.f,0.f}};
    f32x4 accb[4] = {{0.f,0.f,0.f,0.f},{0.f,0.f,0.f,0.f},{0.f,0.f,0.f,0.f},{0.f,0.f,0.f,0.f}};

    for (int k0 = 0; k0 < DMODEL; k0 += 32) {
        __syncthreads();   // previous chunk's readers done
        // stage X (and b_emb): 64 rows x 32 k
#pragma unroll
        for (int i = 0; i < 2; ++i) {
            int id = i * 256 + t;
            int row = id >> 3, k4 = (id & 7) * 4;
            float4 xv = *(const float4*)&X[(s0 + row) * DMODEL + k0 + k4];
            unsigned short h0,l0,h1,l1,h2,l2,h3,l3;
            splitRN(xv.x,h0,l0); splitRN(xv.y,h1,l1);
            splitRN(xv.z,h2,l2); splitRN(xv.w,h3,l3);
            *(ushort4*)&Xh[row][k4] = make_ushort4(h0,h1,h2,h3);
            *(ushort4*)&Xl[row][k4] = make_ushort4(l0,l1,l2,l3);
            if (dorope) {
                float4 bv = *(const float4*)&b_emb[(s0 + row) * DMODEL + k0 + k4];
                splitRN(bv.x,h0,l0); splitRN(bv.y,h1,l1);
                splitRN(bv.z,h2,l2); splitRN(bv.w,h3,l3);
                *(ushort4*)&Bh_[row][k4] = make_ushort4(h0,h1,h2,h3);
                *(ushort4*)&Bl_[row][k4] = make_ushort4(l0,l1,l2,l3);
            }
        }
        // stage W (transposed) (and bproj): 32 k-rows x 64 n
#pragma unroll
        for (int i = 0; i < 2; ++i) {
            int id = i * 256 + t;
            int r = id >> 4, n4 = (id & 15) * 4;
            float4 wv = *(const float4*)&ll[woff + (k0 + r) * DMODEL + h * 64 + n4];
            unsigned short hh, lo_;
#pragma unroll
            for (int m = 0; m < 4; ++m) {
                splitRN((&wv.x)[m], hh, lo_);
                Wh[n4 + m][r] = hh; Wl[n4 + m][r] = lo_;
            }
            if (dorope) {
                float4 pv = *(const float4*)&bproj[(k0 + r) * DMODEL + h * 64 + n4];
#pragma unroll
                for (int m = 0; m < 4; ++m) {
                    splitRN((&pv.x)[m], hh, lo_);
                    Ph[n4 + m][r] = hh; Pl[n4 + m][r] = lo_;
                }
            }
        }
        __syncthreads();

        // A-frags (W^T): m = dt*16+c (head-dim), element j: k = quad*8+j
        bf16x8 Awh = *(bf16x8*)&Wh[dt * 16 + c][quad * 8];
        bf16x8 Awl = *(bf16x8*)&Wl[dt * 16 + c][quad * 8];
        bf16x8 Aph, Apl;
        if (dorope) {
            Aph = *(bf16x8*)&Ph[dt * 16 + c][quad * 8];
            Apl = *(bf16x8*)&Pl[dt * 16 + c][quad * 8];
        }
#pragma unroll
        for (int st = 0; st < 4; ++st) {
            bf16x8 Bxh = *(bf16x8*)&Xh[st * 16 + c][quad * 8];
            bf16x8 Bxl = *(bf16x8*)&Xl[st * 16 + c][quad * 8];
            accx[st] = __builtin_amdgcn_mfma_f32_16x16x32_bf16(Awh, Bxh, accx[st], 0, 0, 0);
            accx[st] = __builtin_amdgcn_mfma_f32_16x16x32_bf16(Awh, Bxl, accx[st], 0, 0, 0);
            accx[st] = __builtin_amdgcn_mfma_f32_16x16x32_bf16(Awl, Bxh, accx[st], 0, 0, 0);
            accx[st] = __builtin_amdgcn_mfma_f32_16x16x32_bf16(Awl, Bxl, accx[st], 0, 0, 0);
            if (dorope) {
                bf16x8 Bbh = *(bf16x8*)&Bh_[st * 16 + c][quad * 8];
                bf16x8 Bbl = *(bf16x8*)&Bl_[st * 16 + c][quad * 8];
                accb[st] = __builtin_amdgcn_mfma_f32_16x16x32_bf16(Aph, Bbh, accb[st], 0, 0, 0);
                accb[st] = __builtin_amdgcn_mfma_f32_16x16x32_bf16(Aph, Bbl, accb[st], 0, 0, 0);
                accb[st] = __builtin_amdgcn_mfma_f32_16x16x32_bf16(Apl, Bbh, accb[st], 0, 0, 0);
                accb[st] = __builtin_amdgcn_mfma_f32_16x16x32_bf16(Apl, Bbl, accb[st], 0, 0, 0);
            }
        }
    }

    // C/D: col=lane&15 = s, row=quad*4+reg = head-dim (within d-tile dt)
    if (mode == 1) {
        int p0 = dt * 8 + 2 * quad;
        double inv0 = pow(10000.0, -(double)p0 / 32.0);
        double inv1 = pow(10000.0, -(double)(p0 + 1) / 32.0);
#pragma unroll
        for (int st = 0; st < 4; ++st) {
            int s = s0 + st * 16 + c;
            double a0 = (double)s * inv0, a1 = (double)s * inv1;
            float sn0 = (float)sin(a0), cs0 = (float)cos(a0);
            float sn1 = (float)sin(a1), cs1 = (float)cos(a1);
            float r0 = (accx[st][0] * cs0 - accx[st][1] * sn0) * accb[st][0];
            float r1 = (accx[st][0] * sn0 + accx[st][1] * cs0) * accb[st][1];
            float r2 = (accx[st][2] * cs1 - accx[st][3] * sn1) * accb[st][2];
            float r3 = (accx[st][2] * sn1 + accx[st][3] * cs1) * accb[st][3];
            unsigned short h0,l0,h1,l1,h2,l2,h3,l3;
            splitRN(r0,h0,l0); splitRN(r1,h1,l1); splitRN(r2,h2,l2); splitRN(r3,h3,l3);
            size_t base = ((size_t)(h * S_LEN + s)) * 64 + dt * 16 + 4 * quad;
            *(ushort4*)&out_hi[base] = make_ushort4(h0,h1,h2,h3);
            *(ushort4*)&out_lo[base] = make_ushort4(l0,l1,l2,l3);
        }
    } else {
        // v: transposed [h][d][s]
#pragma unroll
        for (int st = 0; st < 4; ++st) {
            int s = s0 + st * 16 + c;
#pragma unroll
            for (int reg = 0; reg < 4; ++reg) {
                unsigned short hh, lo_;
                splitRN(accx[st][reg], hh, lo_);
                size_t base = ((size_t)(h * 64 + dt * 16 + 4 * quad + reg)) * S_LEN + s;
                out_hi[base] = hh; out_lo[base] = lo_;
            }
        }
    }
}

// MFMA flash attention: QK 4-MFMA split-bf16, PV 3-MFMA; register softmax; out fp32 [s][h*64+d].
// grid (32 q-tiles, 16 heads), 256 threads = 4 waves (16 q-rows each).
__global__ __launch_bounds__(256)
void attn_mfma(const unsigned short* __restrict__ qh, const unsigned short* __restrict__ ql,
               const unsigned short* __restrict__ kh, const unsigned short* __restrict__ kl,
               const unsigned short* __restrict__ vh, const unsigned short* __restrict__ vl,
               const void* __restrict__ mask, float* __restrict__ out,
               const int* __restrict__ flags) {
    __shared__ unsigned short Kh[64][72], Kl[64][72];   // [key][d]
    __shared__ unsigned short Vh[64][72], Vl[64][72];   // [d][key]
    __shared__ unsigned short Sh[64][72], Sl[64][72];   // P: [q-row][key]
    const int menc = flags[0];
    const int t = threadIdx.x;
    const int h = blockIdx.y;
    const int s0 = blockIdx.x * 64;
    const int lane = t & 63, w = t >> 6, quad = lane >> 4, c = lane & 15;

    // Q fragments in registers for all tiles: A[m=c][k=ks*32+quad*8+j], q-row = s0+16w+c
    bf16x8 qfh[2], qfl[2];
#pragma unroll
    for (int ks = 0; ks < 2; ++ks) {
        size_t base = ((size_t)(h * S_LEN + s0 + 16 * w + c)) * 64 + ks * 32 + quad * 8;
        qfh[ks] = *(const bf16x8*)&qh[base];
        qfl[ks] = *(const bf16x8*)&ql[base];
    }
    int mq[4];
#pragma unroll
    for (int i = 0; i < 4; ++i) mq[i] = mask_at(mask, menc, s0 + 16 * w + quad * 4 + i);

    float m_i[4], l_i[4];
#pragma unroll
    for (int i = 0; i < 4; ++i) { m_i[i] = -INFINITY; l_i[i] = 0.0f; }
    f32x4 o_acc[4] = {{0.f,0.f,0.f,0.f},{0.f,0.f,0.f,0.f},{0.f,0.f,0.f,0.f},{0.f,0.f,0.f,0.f}};

    // prefetch tile 0
    uint4 pre[8];
#pragma unroll
    for (int i = 0; i < 2; ++i) {
        int id = i * 256 + t, row = id >> 3, col8 = (id & 7) * 8;
        size_t kb = ((size_t)(h * S_LEN + row)) * 64 + col8;
        size_t vb = ((size_t)(h * 64 + row)) * S_LEN + col8;
        pre[0 + i] = *(const uint4*)&kh[kb];
        pre[2 + i] = *(const uint4*)&kl[kb];
        pre[4 + i] = *(const uint4*)&vh[vb];
        pre[6 + i] = *(const uint4*)&vl[vb];
    }

    for (int kt = 0; kt < 32; ++kt) {
#pragma unroll
        for (int i = 0; i < 2; ++i) {
            int id = i * 256 + t, row = id >> 3, col8 = (id & 7) * 8;
            *(uint4*)&Kh[row][col8] = pre[0 + i];
            *(uint4*)&Kl[row][col8] = pre[2 + i];
            *(uint4*)&Vh[row][col8] = pre[4 + i];
            *(uint4*)&Vl[row][col8] = pre[6 + i];
        }
        int mk[4];
#pragma unroll
        for (int nt = 0; nt < 4; ++nt) mk[nt] = mask_at(mask, menc, kt * 64 + 16 * nt + c);
        __syncthreads();   // tiles staged

        if (kt + 1 < 32) {
            const int kb0 = (kt + 1) * 64;
#pragma unroll
            for (int i = 0; i < 2; ++i) {
                int id = i * 256 + t, row = id >> 3, col8 = (id & 7) * 8;
                size_t kb = ((size_t)(h * S_LEN + kb0 + row)) * 64 + col8;
                size_t vb = ((size_t)(h * 64 + row)) * S_LEN + kb0 + col8;
                pre[0 + i] = *(const uint4*)&kh[kb];
                pre[2 + i] = *(const uint4*)&kl[kb];
                pre[4 + i] = *(const uint4*)&vh[vb];
                pre[6 + i] = *(const uint4*)&vl[vb];
            }
        }

        // ---- QK^T ----
        f32x4 sc[4] = {{0.f,0.f,0.f,0.f},{0.f,0.f,0.f,0.f},{0.f,0.f,0.f,0.f},{0.f,0.f,0.f,0.f}};
#pragma unroll
        for (int nt = 0; nt < 4; ++nt) {
#pragma unroll
            for (int ks = 0; ks < 2; ++ks) {
                bf16x8 kfh = *(bf16x8*)&Kh[nt * 16 + c][ks * 32 + quad * 8];
                bf16x8 kfl = *(bf16x8*)&Kl[nt * 16 + c][ks * 32 + quad * 8];
                sc[nt] = __builtin_amdgcn_mfma_f32_16x16x32_bf16(qfh[ks], kfh, sc[nt], 0, 0, 0);
                sc[nt] = __builtin_amdgcn_mfma_f32_16x16x32_bf16(qfh[ks], kfl, sc[nt], 0, 0, 0);
                sc[nt] = __builtin_amdgcn_mfma_f32_16x16x32_bf16(qfl[ks], kfh, sc[nt], 0, 0, 0);
                sc[nt] = __builtin_amdgcn_mfma_f32_16x16x32_bf16(qfl[ks], kfl, sc[nt], 0, 0, 0);
            }
        }

        // ---- mask + scale; rows = quad*4+reg, col = 16*nt+c ----
        float sm[4][4];
#pragma unroll
        for (int nt = 0; nt < 4; ++nt)
#pragma unroll
            for (int reg = 0; reg < 4; ++reg)
                sm[nt][reg] = (mq[reg] && mk[nt]) ? sc[nt][reg] * 0.125f : -1e30f;

        float rmax[4];
#pragma unroll
        for (int reg = 0; reg < 4; ++reg)
            rmax[reg] = fmaxf(fmaxf(sm[0][reg], sm[1][reg]), fmaxf(sm[2][reg], sm[3][reg]));
#pragma unroll
        for (int off = 1; off <= 8; off <<= 1)
#pragma unroll
            for (int reg = 0; reg < 4; ++reg)
                rmax[reg] = fmaxf(rmax[reg], __shfl_xor(rmax[reg], off, 64));

        float mn[4], alpha[4];
#pragma unroll
        for (int reg = 0; reg < 4; ++reg) {
            mn[reg] = fmaxf(m_i[reg], rmax[reg]);
            alpha[reg] = __expf(m_i[reg] - mn[reg]);
            m_i[reg] = mn[reg];
        }

        float rsum[4] = {0.f, 0.f, 0.f, 0.f};
#pragma unroll
        for (int nt = 0; nt < 4; ++nt)
#pragma unroll
            for (int reg = 0; reg < 4; ++reg) {
                float e = __expf(sm[nt][reg] - mn[reg]);
                rsum[reg] += e;
                unsigned short eh, el;
                splitRN(e, eh, el);
                Sh[16 * w + quad * 4 + reg][16 * nt + c] = eh;
                Sl[16 * w + quad * 4 + reg][16 * nt + c] = el;
            }
#pragma unroll
        for (int off = 1; off <= 8; off <<= 1)
#pragma unroll
            for (int reg = 0; reg < 4; ++reg)
                rsum[reg] += __shfl_xor(rsum[reg], off, 64);
#pragma unroll
        for (int reg = 0; reg < 4; ++reg) l_i[reg] = l_i[reg] * alpha[reg] + rsum[reg];
#pragma unroll
        for (int nt = 0; nt < 4; ++nt)
#pragma unroll
            for (int reg = 0; reg < 4; ++reg) o_acc[nt][reg] *= alpha[reg];

        __syncthreads();   // P visible

        // ---- PV ----
#pragma unroll
        for (int ks = 0; ks < 2; ++ks) {
            bf16x8 pfh = *(bf16x8*)&Sh[16 * w + c][ks * 32 + quad * 8];
            bf16x8 pfl = *(bf16x8*)&Sl[16 * w + c][ks * 32 + quad * 8];
#pragma unroll
            for (int nt = 0; nt < 4; ++nt) {
                bf16x8 vfh = *(bf16x8*)&Vh[nt * 16 + c][ks * 32 + quad * 8];
                bf16x8 vfl = *(bf16x8*)&Vl[nt * 16 + c][ks * 32 + quad * 8];
                o_acc[nt] = __builtin_amdgcn_mfma_f32_16x16x32_bf16(pfh, vfh, o_acc[nt], 0, 0, 0);
                o_acc[nt] = __builtin_amdgcn_mfma_f32_16x16x32_bf16(pfh, vfl, o_acc[nt], 0, 0, 0);
                o_acc[nt] = __builtin_amdgcn_mfma_f32_16x16x32_bf16(pfl, vfh, o_acc[nt], 0, 0, 0);
            }
        }
        __syncthreads();   // safe to overwrite K/V/S
    }

#pragma unroll
    for (int reg = 0; reg < 4; ++reg) {
        float inv = 1.0f / l_i[reg];
        int row = s0 + 16 * w + quad * 4 + reg;
#pragma unroll
        for (int nt = 0; nt < 4; ++nt)
            out[(size_t)row * 1024 + h * 64 + nt * 16 + c] = o_acc[nt][reg] * inv;
    }
}

extern "C" void kernel_launch(void* const* d_in, const int* in_sizes, int n_in,
                              void* d_out, int out_size, void* d_ws, size_t ws_size,
                              hipStream_t stream) {
    const float* query = (const float*)d_in[0];
    const float* key   = (const float*)d_in[1];
    const float* value = (const float*)d_in[2];
    const float* b_emb = (const float*)d_in[3];
    const void*  mask  = d_in[4];
    const float* ll    = (const float*)d_in[5];
    const float* bproj = (const float*)d_in[6];
    float* out = (float*)d_out;

    const size_t HSD = (size_t)NHEAD * S_LEN * 64;   // 2M elements
    int* flags = (int*)d_ws;
    unsigned short* qhi = (unsigned short*)((char*)d_ws + 4096);
    unsigned short* qlo = qhi + HSD;
    unsigned short* khi = qlo + HSD;
    unsigned short* klo = khi + HSD;
    unsigned short* vhi = klo + HSD;
    unsigned short* vlo = vhi + HSD;   // total 24 MB + 4 KB

    dim3 pb(256), pg(16, 32);
    detect_kernel<<<1, 64, 0, stream>>>(mask, flags);
    proj_mfma<<<pg, pb, 0, stream>>>(query, b_emb, ll, bproj, qhi, qlo, 0 * 1048576, 1);
    proj_mfma<<<pg, pb, 0, stream>>>(key,   b_emb, ll, bproj, khi, klo, 1 * 1048576, 1);
    proj_mfma<<<pg, pb, 0, stream>>>(value, b_emb, ll, bproj, vhi, vlo, 2 * 1048576, 0);
    attn_mfma<<<dim3(32, 16), pb, 0, stream>>>(qhi, qlo, khi, klo, vhi, vlo, mask, out, flags);
}

// Round 10
// 493.727 us; speedup vs baseline: 1.2770x; 1.2770x over previous
//
#include <hip/hip_runtime.h>
#include <hip/hip_bf16.h>
#include <math.h>

#define S_LEN 2048
#define NHEAD 16
#define DMODEL 1024

typedef short bf16x8 __attribute__((ext_vector_type(8)));
typedef float f32x4 __attribute__((ext_vector_type(4)));

static __device__ __forceinline__ unsigned short bfbits(float x) {
    __hip_bfloat16 h = __float2bfloat16(x);   // round-to-nearest
    unsigned short u; __builtin_memcpy(&u, &h, 2); return u;
}
static __device__ __forceinline__ float bf2f(unsigned short u) {
    union { unsigned int i; float f; } v; v.i = ((unsigned int)u) << 16; return v.f;
}
// round-to-nearest split: x ~= hi + lo, rel err ~2^-18
static __device__ __forceinline__ void splitRN(float x, unsigned short& hi, unsigned short& lo) {
    unsigned short h = bfbits(x);
    float r = x - bf2f(h);
    hi = h; lo = bfbits(r);
}

__device__ __forceinline__ int mask_at(const void* mp, int enc, int s) {
    if (enc) return ((const unsigned char*)mp)[s] != 0;
    return ((const unsigned int*)mp)[s] != 0u;
}

__global__ void detect_kernel(const void* __restrict__ mask, int* __restrict__ flags) {
    if (threadIdx.x == 0 && blockIdx.x == 0) {
        const unsigned int* m = (const unsigned int*)mask;
        int bytey = 0;
        for (int i = 0; i < 8; ++i) {
            unsigned int u = m[i];
            if (u != 0u && u != 1u && u != 0x3F800000u) bytey = 1;
        }
        flags[0] = bytey;
    }
}

// Fused q/k/v/b_rotate projection. One block = one (head, 64-row s-tile).
// q,k: RN hi/lo bf16 [h][s][d] (RoPE*b fused). v: bf16-hi [h][d][s] (transposed, coalesced).
// 256 threads = 4 waves (16-head-dim d-tiles). LDS pool = 75 KB, reused for v transpose.
__global__ __launch_bounds__(256)
void proj_fused(const float* __restrict__ Xq, const float* __restrict__ Xk,
                const float* __restrict__ Xv, const float* __restrict__ Xb,
                const float* __restrict__ ll, const float* __restrict__ bproj,
                unsigned short* __restrict__ qhi, unsigned short* __restrict__ qlo,
                unsigned short* __restrict__ khi, unsigned short* __restrict__ klo,
                unsigned short* __restrict__ vhi) {
    __shared__ unsigned short smem[15 * 2560];   // 15 arrays of [64][40]
    unsigned short (*XQh)[40] = (unsigned short(*)[40])(smem + 0 * 2560);
    unsigned short (*XQl)[40] = (unsigned short(*)[40])(smem + 1 * 2560);
    unsigned short (*XKh)[40] = (unsigned short(*)[40])(smem + 2 * 2560);
    unsigned short (*XKl)[40] = (unsigned short(*)[40])(smem + 3 * 2560);
    unsigned short (*XVh)[40] = (unsigned short(*)[40])(smem + 4 * 2560);
    unsigned short (*XBh)[40] = (unsigned short(*)[40])(smem + 5 * 2560);
    unsigned short (*XBl)[40] = (unsigned short(*)[40])(smem + 6 * 2560);
    unsigned short (*WQh)[40] = (unsigned short(*)[40])(smem + 7 * 2560);
    unsigned short (*WQl)[40] = (unsigned short(*)[40])(smem + 8 * 2560);
    unsigned short (*WKh)[40] = (unsigned short(*)[40])(smem + 9 * 2560);
    unsigned short (*WKl)[40] = (unsigned short(*)[40])(smem + 10 * 2560);
    unsigned short (*WVh)[40] = (unsigned short(*)[40])(smem + 11 * 2560);
    unsigned short (*WVl)[40] = (unsigned short(*)[40])(smem + 12 * 2560);
    unsigned short (*WBh)[40] = (unsigned short(*)[40])(smem + 13 * 2560);
    unsigned short (*WBl)[40] = (unsigned short(*)[40])(smem + 14 * 2560);
    unsigned short (*Vscr)[72] = (unsigned short(*)[72])smem;   // epilogue reuse

    const int t = threadIdx.x;
    const int h = blockIdx.x;
    const int s0 = blockIdx.y * 64;
    const int lane = t & 63, dt = t >> 6, quad = lane >> 4, c = lane & 15;

    f32x4 aq[4], ak[4], av[4], ab[4];
#pragma unroll
    for (int i = 0; i < 4; ++i) {
        aq[i] = (f32x4){0.f,0.f,0.f,0.f}; ak[i] = (f32x4){0.f,0.f,0.f,0.f};
        av[i] = (f32x4){0.f,0.f,0.f,0.f}; ab[i] = (f32x4){0.f,0.f,0.f,0.f};
    }

    for (int k0 = 0; k0 < DMODEL; k0 += 32) {
        __syncthreads();   // previous chunk's LDS readers done
        // X tiles: 64 rows x 32 k, split once
#pragma unroll
        for (int i = 0; i < 2; ++i) {
            int id = i * 256 + t, row = id >> 3, k4 = (id & 7) * 4;
            int g = (s0 + row) * DMODEL + k0 + k4;
            unsigned short h0,l0,h1,l1,h2,l2,h3,l3;
            float4 x = *(const float4*)&Xq[g];
            splitRN(x.x,h0,l0); splitRN(x.y,h1,l1); splitRN(x.z,h2,l2); splitRN(x.w,h3,l3);
            *(ushort4*)&XQh[row][k4] = make_ushort4(h0,h1,h2,h3);
            *(ushort4*)&XQl[row][k4] = make_ushort4(l0,l1,l2,l3);
            x = *(const float4*)&Xk[g];
            splitRN(x.x,h0,l0); splitRN(x.y,h1,l1); splitRN(x.z,h2,l2); splitRN(x.w,h3,l3);
            *(ushort4*)&XKh[row][k4] = make_ushort4(h0,h1,h2,h3);
            *(ushort4*)&XKl[row][k4] = make_ushort4(l0,l1,l2,l3);
            x = *(const float4*)&Xv[g];
            *(ushort4*)&XVh[row][k4] = make_ushort4(bfbits(x.x),bfbits(x.y),bfbits(x.z),bfbits(x.w));
            x = *(const float4*)&Xb[g];
            splitRN(x.x,h0,l0); splitRN(x.y,h1,l1); splitRN(x.z,h2,l2); splitRN(x.w,h3,l3);
            *(ushort4*)&XBh[row][k4] = make_ushort4(h0,h1,h2,h3);
            *(ushort4*)&XBl[row][k4] = make_ushort4(l0,l1,l2,l3);
        }
        // W tiles (transposed [n][k]): 32 k-rows x 64 n
#pragma unroll
        for (int i = 0; i < 2; ++i) {
            int id = i * 256 + t, r = id >> 4, n4 = (id & 15) * 4;
            int g = (k0 + r) * DMODEL + h * 64 + n4;
            unsigned short hh, lo2;
            float4 w = *(const float4*)&ll[g];
#pragma unroll
            for (int m = 0; m < 4; ++m) { splitRN((&w.x)[m],hh,lo2); WQh[n4+m][r]=hh; WQl[n4+m][r]=lo2; }
            w = *(const float4*)&ll[1048576 + g];
#pragma unroll
            for (int m = 0; m < 4; ++m) { splitRN((&w.x)[m],hh,lo2); WKh[n4+m][r]=hh; WKl[n4+m][r]=lo2; }
            w = *(const float4*)&ll[2097152 + g];
#pragma unroll
            for (int m = 0; m < 4; ++m) { splitRN((&w.x)[m],hh,lo2); WVh[n4+m][r]=hh; WVl[n4+m][r]=lo2; }
            w = *(const float4*)&bproj[g];
#pragma unroll
            for (int m = 0; m < 4; ++m) { splitRN((&w.x)[m],hh,lo2); WBh[n4+m][r]=hh; WBl[n4+m][r]=lo2; }
        }
        __syncthreads();

        bf16x8 aQh = *(bf16x8*)&WQh[dt*16+c][quad*8], aQl = *(bf16x8*)&WQl[dt*16+c][quad*8];
        bf16x8 aKh = *(bf16x8*)&WKh[dt*16+c][quad*8], aKl = *(bf16x8*)&WKl[dt*16+c][quad*8];
        bf16x8 aVh = *(bf16x8*)&WVh[dt*16+c][quad*8], aVl = *(bf16x8*)&WVl[dt*16+c][quad*8];
        bf16x8 aBh = *(bf16x8*)&WBh[dt*16+c][quad*8], aBl = *(bf16x8*)&WBl[dt*16+c][quad*8];
#pragma unroll
        for (int st = 0; st < 4; ++st) {
            bf16x8 b1 = *(bf16x8*)&XQh[st*16+c][quad*8];
            bf16x8 b2 = *(bf16x8*)&XQl[st*16+c][quad*8];
            aq[st] = __builtin_amdgcn_mfma_f32_16x16x32_bf16(aQh, b1, aq[st], 0, 0, 0);
            aq[st] = __builtin_amdgcn_mfma_f32_16x16x32_bf16(aQh, b2, aq[st], 0, 0, 0);
            aq[st] = __builtin_amdgcn_mfma_f32_16x16x32_bf16(aQl, b1, aq[st], 0, 0, 0);
            aq[st] = __builtin_amdgcn_mfma_f32_16x16x32_bf16(aQl, b2, aq[st], 0, 0, 0);
            b1 = *(bf16x8*)&XKh[st*16+c][quad*8];
            b2 = *(bf16x8*)&XKl[st*16+c][quad*8];
            ak[st] = __builtin_amdgcn_mfma_f32_16x16x32_bf16(aKh, b1, ak[st], 0, 0, 0);
            ak[st] = __builtin_amdgcn_mfma_f32_16x16x32_bf16(aKh, b2, ak[st], 0, 0, 0);
            ak[st] = __builtin_amdgcn_mfma_f32_16x16x32_bf16(aKl, b1, ak[st], 0, 0, 0);
            ak[st] = __builtin_amdgcn_mfma_f32_16x16x32_bf16(aKl, b2, ak[st], 0, 0, 0);
            b1 = *(bf16x8*)&XVh[st*16+c][quad*8];
            av[st] = __builtin_amdgcn_mfma_f32_16x16x32_bf16(aVh, b1, av[st], 0, 0, 0);
            av[st] = __builtin_amdgcn_mfma_f32_16x16x32_bf16(aVl, b1, av[st], 0, 0, 0);
            b1 = *(bf16x8*)&XBh[st*16+c][quad*8];
            b2 = *(bf16x8*)&XBl[st*16+c][quad*8];
            ab[st] = __builtin_amdgcn_mfma_f32_16x16x32_bf16(aBh, b1, ab[st], 0, 0, 0);
            ab[st] = __builtin_amdgcn_mfma_f32_16x16x32_bf16(aBh, b2, ab[st], 0, 0, 0);
            ab[st] = __builtin_amdgcn_mfma_f32_16x16x32_bf16(aBl, b1, ab[st], 0, 0, 0);
            ab[st] = __builtin_amdgcn_mfma_f32_16x16x32_bf16(aBl, b2, ab[st], 0, 0, 0);
        }
    }

    // ---- q/k epilogue: RoPE * b, RN hi/lo stores (register-only) ----
    {
        int p0 = dt * 8 + 2 * quad;
        double inv0 = pow(10000.0, -(double)p0 / 32.0);
        double inv1 = pow(10000.0, -(double)(p0 + 1) / 32.0);
#pragma unroll
        for (int st = 0; st < 4; ++st) {
            int s = s0 + st * 16 + c;
            double a0 = (double)s * inv0, a1 = (double)s * inv1;
            float sn0 = (float)sin(a0), cs0 = (float)cos(a0);
            float sn1 = (float)sin(a1), cs1 = (float)cos(a1);
            size_t base = ((size_t)(h * S_LEN + s)) * 64 + dt * 16 + 4 * quad;
            unsigned short h0,l0,h1,l1,h2,l2,h3,l3;
            float r0 = (aq[st][0]*cs0 - aq[st][1]*sn0) * ab[st][0];
            float r1 = (aq[st][0]*sn0 + aq[st][1]*cs0) * ab[st][1];
            float r2 = (aq[st][2]*cs1 - aq[st][3]*sn1) * ab[st][2];
            float r3 = (aq[st][2]*sn1 + aq[st][3]*cs1) * ab[st][3];
            splitRN(r0,h0,l0); splitRN(r1,h1,l1); splitRN(r2,h2,l2); splitRN(r3,h3,l3);
            *(ushort4*)&qhi[base] = make_ushort4(h0,h1,h2,h3);
            *(ushort4*)&qlo[base] = make_ushort4(l0,l1,l2,l3);
            r0 = (ak[st][0]*cs0 - ak[st][1]*sn0) * ab[st][0];
            r1 = (ak[st][0]*sn0 + ak[st][1]*cs0) * ab[st][1];
            r2 = (ak[st][2]*cs1 - ak[st][3]*sn1) * ab[st][2];
            r3 = (ak[st][2]*sn1 + ak[st][3]*cs1) * ab[st][3];
            splitRN(r0,h0,l0); splitRN(r1,h1,l1); splitRN(r2,h2,l2); splitRN(r3,h3,l3);
            *(ushort4*)&khi[base] = make_ushort4(h0,h1,h2,h3);
            *(ushort4*)&klo[base] = make_ushort4(l0,l1,l2,l3);
        }
    }

    // ---- v epilogue: LDS transpose -> coalesced [h][d][s] uint4 stores ----
    __syncthreads();   // all MFMA LDS reads done; safe to reuse pool
#pragma unroll
    for (int st = 0; st < 4; ++st)
#pragma unroll
        for (int reg = 0; reg < 4; ++reg)
            Vscr[dt * 16 + 4 * quad + reg][st * 16 + c] = bfbits(av[st][reg]);
    __syncthreads();
#pragma unroll
    for (int i = 0; i < 2; ++i) {
        int id = i * 256 + t, d = id >> 3, s8 = (id & 7) * 8;
        size_t gb = ((size_t)(h * 64 + d)) * S_LEN + s0 + s8;
        *(uint4*)&vhi[gb] = *(uint4*)&Vscr[d][s8];
    }
}

// MFMA flash attention: QK 3-MFMA split-bf16, PV 2-MFMA (V hi-only); register softmax.
// out fp32 [s][h*64+d]. grid (32 q-tiles, 16 heads), 256 threads.
__global__ __launch_bounds__(256)
void attn_mfma(const unsigned short* __restrict__ qh, const unsigned short* __restrict__ ql,
               const unsigned short* __restrict__ kh, const unsigned short* __restrict__ kl,
               const unsigned short* __restrict__ vh,
               const void* __restrict__ mask, float* __restrict__ out,
               const int* __restrict__ flags) {
    __shared__ unsigned short Kh[64][72], Kl[64][72];   // [key][d]
    __shared__ unsigned short Vt[64][72];               // [d][key]
    __shared__ unsigned short Sh[64][72], Sl[64][72];   // P: [q-row][key]
    const int menc = flags[0];
    const int t = threadIdx.x;
    const int h = blockIdx.y;
    const int s0 = blockIdx.x * 64;
    const int lane = t & 63, w = t >> 6, quad = lane >> 4, c = lane & 15;

    bf16x8 qfh[2], qfl[2];
#pragma unroll
    for (int ks = 0; ks < 2; ++ks) {
        size_t base = ((size_t)(h * S_LEN + s0 + 16 * w + c)) * 64 + ks * 32 + quad * 8;
        qfh[ks] = *(const bf16x8*)&qh[base];
        qfl[ks] = *(const bf16x8*)&ql[base];
    }
    int mq[4];
#pragma unroll
    for (int i = 0; i < 4; ++i) mq[i] = mask_at(mask, menc, s0 + 16 * w + quad * 4 + i);

    float m_i[4], l_i[4];
#pragma unroll
    for (int i = 0; i < 4; ++i) { m_i[i] = -INFINITY; l_i[i] = 0.0f; }
    f32x4 o_acc[4];
#pragma unroll
    for (int i = 0; i < 4; ++i) o_acc[i] = (f32x4){0.f,0.f,0.f,0.f};

    uint4 pre[6];
#pragma unroll
    for (int i = 0; i < 2; ++i) {
        int id = i * 256 + t, row = id >> 3, col8 = (id & 7) * 8;
        size_t kb = ((size_t)(h * S_LEN + row)) * 64 + col8;
        size_t vb = ((size_t)(h * 64 + row)) * S_LEN + col8;
        pre[0 + i] = *(const uint4*)&kh[kb];
        pre[2 + i] = *(const uint4*)&kl[kb];
        pre[4 + i] = *(const uint4*)&vh[vb];
    }

    for (int kt = 0; kt < 32; ++kt) {
#pragma unroll
        for (int i = 0; i < 2; ++i) {
            int id = i * 256 + t, row = id >> 3, col8 = (id & 7) * 8;
            *(uint4*)&Kh[row][col8] = pre[0 + i];
            *(uint4*)&Kl[row][col8] = pre[2 + i];
            *(uint4*)&Vt[row][col8] = pre[4 + i];
        }
        int mk[4];
#pragma unroll
        for (int nt = 0; nt < 4; ++nt) mk[nt] = mask_at(mask, menc, kt * 64 + 16 * nt + c);
        __syncthreads();

        if (kt + 1 < 32) {
            const int kb0 = (kt + 1) * 64;
#pragma unroll
            for (int i = 0; i < 2; ++i) {
                int id = i * 256 + t, row = id >> 3, col8 = (id & 7) * 8;
                size_t kb = ((size_t)(h * S_LEN + kb0 + row)) * 64 + col8;
                size_t vb = ((size_t)(h * 64 + row)) * S_LEN + kb0 + col8;
                pre[0 + i] = *(const uint4*)&kh[kb];
                pre[2 + i] = *(const uint4*)&kl[kb];
                pre[4 + i] = *(const uint4*)&vh[vb];
            }
        }

        // ---- QK^T (3-MFMA split) ----
        f32x4 sc[4];
#pragma unroll
        for (int i = 0; i < 4; ++i) sc[i] = (f32x4){0.f,0.f,0.f,0.f};
#pragma unroll
        for (int nt = 0; nt < 4; ++nt)
#pragma unroll
            for (int ks = 0; ks < 2; ++ks) {
                bf16x8 kfh = *(bf16x8*)&Kh[nt * 16 + c][ks * 32 + quad * 8];
                bf16x8 kfl = *(bf16x8*)&Kl[nt * 16 + c][ks * 32 + quad * 8];
                sc[nt] = __builtin_amdgcn_mfma_f32_16x16x32_bf16(qfh[ks], kfh, sc[nt], 0, 0, 0);
                sc[nt] = __builtin_amdgcn_mfma_f32_16x16x32_bf16(qfh[ks], kfl, sc[nt], 0, 0, 0);
                sc[nt] = __builtin_amdgcn_mfma_f32_16x16x32_bf16(qfl[ks], kfh, sc[nt], 0, 0, 0);
            }

        float sm[4][4];
#pragma unroll
        for (int nt = 0; nt < 4; ++nt)
#pragma unroll
            for (int reg = 0; reg < 4; ++reg)
                sm[nt][reg] = (mq[reg] && mk[nt]) ? sc[nt][reg] * 0.125f : -1e30f;

        float rmax[4];
#pragma unroll
        for (int reg = 0; reg < 4; ++reg)
            rmax[reg] = fmaxf(fmaxf(sm[0][reg], sm[1][reg]), fmaxf(sm[2][reg], sm[3][reg]));
#pragma unroll
        for (int off = 1; off <= 8; off <<= 1)
#pragma unroll
            for (int reg = 0; reg < 4; ++reg)
                rmax[reg] = fmaxf(rmax[reg], __shfl_xor(rmax[reg], off, 64));

        float mn[4], alpha[4];
#pragma unroll
        for (int reg = 0; reg < 4; ++reg) {
            mn[reg] = fmaxf(m_i[reg], rmax[reg]);
            alpha[reg] = __expf(m_i[reg] - mn[reg]);
            m_i[reg] = mn[reg];
        }

        float rsum[4] = {0.f, 0.f, 0.f, 0.f};
#pragma unroll
        for (int nt = 0; nt < 4; ++nt)
#pragma unroll
            for (int reg = 0; reg < 4; ++reg) {
                float e = __expf(sm[nt][reg] - mn[reg]);
                rsum[reg] += e;
                unsigned short eh, el;
                splitRN(e, eh, el);
                Sh[16 * w + quad * 4 + reg][16 * nt + c] = eh;
                Sl[16 * w + quad * 4 + reg][16 * nt + c] = el;
            }
#pragma unroll
        for (int off = 1; off <= 8; off <<= 1)
#pragma unroll
            for (int reg = 0; reg < 4; ++reg)
                rsum[reg] += __shfl_xor(rsum[reg], off, 64);
#pragma unroll
        for (int reg = 0; reg < 4; ++reg) l_i[reg] = l_i[reg] * alpha[reg] + rsum[reg];
#pragma unroll
        for (int nt = 0; nt < 4; ++nt)
#pragma unroll
            for (int reg = 0; reg < 4; ++reg) o_acc[nt][reg] *= alpha[reg];

        __syncthreads();   // P visible

        // ---- PV (2-MFMA, V hi-only) ----
#pragma unroll
        for (int ks = 0; ks < 2; ++ks) {
            bf16x8 pfh = *(bf16x8*)&Sh[16 * w + c][ks * 32 + quad * 8];
            bf16x8 pfl = *(bf16x8*)&Sl[16 * w + c][ks * 32 + quad * 8];
#pragma unroll
            for (int nt = 0; nt < 4; ++nt) {
                bf16x8 vf = *(bf16x8*)&Vt[nt * 16 + c][ks * 32 + quad * 8];
                o_acc[nt] = __builtin_amdgcn_mfma_f32_16x16x32_bf16(pfh, vf, o_acc[nt], 0, 0, 0);
                o_acc[nt] = __builtin_amdgcn_mfma_f32_16x16x32_bf16(pfl, vf, o_acc[nt], 0, 0, 0);
            }
        }
        __syncthreads();   // safe to overwrite K/V/S
    }

#pragma unroll
    for (int reg = 0; reg < 4; ++reg) {
        float inv = 1.0f / l_i[reg];
        int row = s0 + 16 * w + quad * 4 + reg;
#pragma unroll
        for (int nt = 0; nt < 4; ++nt)
            out[(size_t)row * 1024 + h * 64 + nt * 16 + c] = o_acc[nt][reg] * inv;
    }
}

extern "C" void kernel_launch(void* const* d_in, const int* in_sizes, int n_in,
                              void* d_out, int out_size, void* d_ws, size_t ws_size,
                              hipStream_t stream) {
    const float* query = (const float*)d_in[0];
    const float* key   = (const float*)d_in[1];
    const float* value = (const float*)d_in[2];
    const float* b_emb = (const float*)d_in[3];
    const void*  mask  = d_in[4];
    const float* ll    = (const float*)d_in[5];
    const float* bproj = (const float*)d_in[6];
    float* out = (float*)d_out;

    const size_t HSD = (size_t)NHEAD * S_LEN * 64;   // 2M elements
    int* flags = (int*)d_ws;
    unsigned short* qhi = (unsigned short*)((char*)d_ws + 4096);
    unsigned short* qlo = qhi + HSD;
    unsigned short* khi = qlo + HSD;
    unsigned short* klo = khi + HSD;
    unsigned short* vhi = klo + HSD;   // total 20 MB + 4 KB

    dim3 pb(256);
    detect_kernel<<<1, 64, 0, stream>>>(mask, flags);
    proj_fused<<<dim3(16, 32), pb, 0, stream>>>(query, key, value, b_emb, ll, bproj,
                                                qhi, qlo, khi, klo, vhi);
    attn_mfma<<<dim3(32, 16), pb, 0, stream>>>(qhi, qlo, khi, klo, vhi, mask, out, flags);
}